// Round 3
// baseline (507.759 us; speedup 1.0000x reference)
//
#include <hip/hip_runtime.h>

// GroupSparseActivation: x (32,2048,1024) fp32.
// Per (b, group of 64 ch): L2 norm over channels at each s, top-K=256 along S,
// binary mask, multiply.
//   k1: exact double sum-of-squares -> fp32 norm n32 = sqrtf((float)sum + 1e-9f)
//       (replicates the reference's float32 norm incl. sqrt tie-merging)
//   k2: one wave per (b,g) row: radix binary search on composite 42-bit key
//       (n32 bits << 11) | (2047 - s)  -> value-desc, index-asc, all distinct
//   k3: masked passthrough; unselected lanes skip the x load entirely

#define BB 32
#define SS 2048
#define CC 1024
#define GG 16
#define KTOP 256
#define NROWS (BB * GG)  // 512

__device__ inline double shfl_xor_dbl(double v, int m) {
  union {
    double d;
    int i[2];
  } u;
  u.d = v;
  u.i[0] = __shfl_xor(u.i[0], m, 64);
  u.i[1] = __shfl_xor(u.i[1], m, 64);
  return u.d;
}

// grid: BB*SS/16 = 4096 blocks, 256 threads. Block handles 16 consecutive
// (b,s); thread t covers channels [4t,4t+4); 16-lane butterfly -> group sum.
__global__ __launch_bounds__(256) void k1_norms(const float4* __restrict__ x4,
                                                float* __restrict__ norms) {
  __shared__ float tile[GG][17];  // [g][i], +1 pad vs bank conflicts
  const int t = threadIdx.x;
  const int bs0 = blockIdx.x * 16;  // b*SS + s0

  for (int i = 0; i < 16; ++i) {
    float4 v = x4[(size_t)(bs0 + i) * 256 + t];
    double d = (double)v.x * v.x + (double)v.y * v.y + (double)v.z * v.z +
               (double)v.w * v.w;
    d += shfl_xor_dbl(d, 1);
    d += shfl_xor_dbl(d, 2);
    d += shfl_xor_dbl(d, 4);
    d += shfl_xor_dbl(d, 8);
    if ((t & 15) == 0) {
      // fp32 norm exactly as the fp32 reference computes it (modulo +-1ulp
      // of the fp32 summation tree): round exact sum to fp32, +EPS, sqrt
      float s32 = (float)d;
      tile[t >> 4][i] = sqrtf(__fadd_rn(s32, 1e-9f));
    }
  }
  __syncthreads();
  {
    const int g = t >> 4;            // 0..15
    const int i = t & 15;            // 0..15
    const int b = bs0 >> 11;         // /2048
    const int s = (bs0 & 2047) + i;  // s0 + i
    // row-major by row=(b*GG+g): 16 lanes write 64 contiguous bytes
    norms[((size_t)(b * GG + g)) * SS + s] = tile[g][i];
  }
}

// grid: NROWS/4 = 128 blocks x 256 threads; each wave owns one row of 2048
// norms. Composite key: (norm bits << 11) | (2047 - s). Norms positive ->
// bit pattern order-preserving; low bits give lowest-index-first tie-break
// (matches jax.lax.top_k / stable argsort). All keys distinct -> top-K is
// exactly key >= T where T = K-th largest key (42-bit radix search).
__global__ __launch_bounds__(256) void k2_topk(const float* __restrict__ norms,
                                               unsigned char* __restrict__ maskT) {
  const int lane = threadIdx.x & 63;
  const int wave = threadIdx.x >> 6;
  const int r = blockIdx.x * 4 + wave;  // 0..511
  const float* rowp = norms + (size_t)r * SS;

  unsigned long long key[32];
#pragma unroll
  for (int j = 0; j < 32; ++j) {
    const int s = j * 64 + lane;
    key[j] = ((unsigned long long)__float_as_uint(rowp[s]) << 11) |
             (unsigned)(SS - 1 - s);
  }

  // T = K-th largest key: max T with count(key >= T) >= KTOP
  unsigned long long T = 0ULL;
  for (int bit = 41; bit >= 0; --bit) {
    unsigned long long cand = T | (1ULL << bit);
    int local = 0;
#pragma unroll
    for (int j = 0; j < 32; ++j) local += (key[j] >= cand) ? 1 : 0;
    for (int m = 32; m >= 1; m >>= 1) local += __shfl_xor(local, m, 64);
    if (local >= KTOP) T = cand;
  }

  const int b = r >> 4;
  const int g = r & 15;
  unsigned char* mrow = maskT + (size_t)b * SS * GG + g;
#pragma unroll
  for (int j = 0; j < 32; ++j) {
    const int s = j * 64 + lane;
    mrow[(size_t)s * GG] = (key[j] >= T) ? (unsigned char)1 : (unsigned char)0;
  }
}

// grid: BB*SS = 65536 blocks x 256 threads; block == one (b,s), thread = one
// float4. Unselected groups write zeros without reading x (exec-masked load).
__global__ __launch_bounds__(256) void k3_apply(const float4* __restrict__ x4,
                                                const unsigned char* __restrict__ maskT,
                                                float4* __restrict__ out4) {
  const int t = threadIdx.x;
  const int bs = blockIdx.x;
  const size_t f = (size_t)bs * 256 + t;
  const int g = t >> 4;
  const unsigned char m = maskT[(size_t)bs * GG + g];
  float4 v = make_float4(0.f, 0.f, 0.f, 0.f);
  if (m) v = x4[f];
  out4[f] = v;
}

extern "C" void kernel_launch(void* const* d_in, const int* in_sizes, int n_in,
                              void* d_out, int out_size, void* d_ws, size_t ws_size,
                              hipStream_t stream) {
  const float* x = (const float*)d_in[0];
  float* out = (float*)d_out;
  float* norms = (float*)d_ws;  // 512*2048*4 = 4 MiB
  unsigned char* maskT =
      (unsigned char*)d_ws + (size_t)NROWS * SS * sizeof(float);  // +1 MiB

  k1_norms<<<BB * SS / 16, 256, 0, stream>>>((const float4*)x, norms);
  k2_topk<<<NROWS / 4, 256, 0, stream>>>(norms, maskT);
  k3_apply<<<BB * SS, 256, 0, stream>>>((const float4*)x, maskT, (float4*)out);
}

// Round 4
// 482.759 us; speedup vs baseline: 1.0518x; 1.0518x over previous
//
#include <hip/hip_runtime.h>

// GroupSparseActivation: x (32,2048,1024) fp32, fully fused.
// One block per (b, g) row (512 blocks, 512 threads):
//   phase A: stream x[b, :, g*64:(g+1)*64] (512 KiB), fp32 norms -> LDS
//            norm = sqrtf((float)exact_double_sumsq + 1e-9f)  [round-3 exact]
//   phase B: wave 0: 42-bit radix search on composite key
//            (norm bits << 11) | (2047 - s)  -> value-desc, index-asc, distinct
//   phase C: re-read selected s only (L2/L3-hot), write masked out
//
// Mandatory HBM traffic: 256 MiB read + 256 MiB write (+ ~0-32 MiB re-read
// if L3 evicts) => ~85 us floor at 6.3 TB/s.

#define BB 32
#define SS 2048
#define CC 1024
#define GG 16
#define KTOP 256

__device__ inline double shfl_xor_dbl(double v, int m) {
  union {
    double d;
    int i[2];
  } u;
  u.d = v;
  u.i[0] = __shfl_xor(u.i[0], m, 64);
  u.i[1] = __shfl_xor(u.i[1], m, 64);
  return u.d;
}

__global__ __launch_bounds__(512) void gsa_fused(const float4* __restrict__ x4,
                                                 float4* __restrict__ out4) {
  __shared__ float norm[SS];  // 8 KiB
  __shared__ unsigned long long Tsh;
  const int t = threadIdx.x;
  const int lane16 = t & 15;  // float4 chunk within the 64-ch group
  const int srow = t >> 4;    // 0..31: s-offset within an iteration
  const int b = blockIdx.x >> 4;
  const int g = blockIdx.x & 15;
  const size_t bbase = (size_t)b * SS;  // (b*SS + s) row index
  const int chunk = g * 16 + lane16;    // float4 index within a 256-float4 row

  // Phase A: norms. Each iter: 32 s-values x 16 lanes; 16-lane butterfly sum.
  for (int it = 0; it < SS / 32; ++it) {
    const int s = it * 32 + srow;
    float4 v = x4[(bbase + s) * 256 + chunk];
    double d = (double)v.x * v.x + (double)v.y * v.y + (double)v.z * v.z +
               (double)v.w * v.w;
    d += shfl_xor_dbl(d, 1);
    d += shfl_xor_dbl(d, 2);
    d += shfl_xor_dbl(d, 4);
    d += shfl_xor_dbl(d, 8);
    if (lane16 == 0) norm[s] = sqrtf(__fadd_rn((float)d, 1e-9f));
  }
  __syncthreads();

  // Phase B: wave 0 finds T = K-th largest composite key (all keys distinct).
  if (t < 64) {
    unsigned long long key[32];
#pragma unroll
    for (int j = 0; j < 32; ++j) {
      const int s = j * 64 + t;
      key[j] = ((unsigned long long)__float_as_uint(norm[s]) << 11) |
               (unsigned)(SS - 1 - s);
    }
    unsigned long long T = 0ULL;
    for (int bit = 41; bit >= 0; --bit) {
      unsigned long long cand = T | (1ULL << bit);
      int local = 0;
#pragma unroll
      for (int j = 0; j < 32; ++j) local += (key[j] >= cand) ? 1 : 0;
      for (int m = 32; m >= 1; m >>= 1) local += __shfl_xor(local, m, 64);
      if (local >= KTOP) T = cand;
    }
    if (t == 0) Tsh = T;
  }
  __syncthreads();
  const unsigned long long T = Tsh;

  // Phase C: masked passthrough; unselected lanes skip the load entirely.
  for (int it = 0; it < SS / 32; ++it) {
    const int s = it * 32 + srow;
    const unsigned long long key =
        ((unsigned long long)__float_as_uint(norm[s]) << 11) |
        (unsigned)(SS - 1 - s);
    float4 v = make_float4(0.f, 0.f, 0.f, 0.f);
    if (key >= T) v = x4[(bbase + s) * 256 + chunk];
    out4[(bbase + s) * 256 + chunk] = v;
  }
}

extern "C" void kernel_launch(void* const* d_in, const int* in_sizes, int n_in,
                              void* d_out, int out_size, void* d_ws, size_t ws_size,
                              hipStream_t stream) {
  const float* x = (const float*)d_in[0];
  float* out = (float*)d_out;
  gsa_fused<<<BB * GG, 512, 0, stream>>>((const float4*)x, (float4*)out);
}